// Round 1
// baseline (593.728 us; speedup 1.0000x reference)
//
#include <hip/hip_runtime.h>
#include <hip/hip_bf16.h>
#include <cmath>

typedef __bf16 bf16;
typedef __bf16 bf16x8 __attribute__((ext_vector_type(8)));
typedef float f32x4 __attribute__((ext_vector_type(4)));

#define BB 4
#define CC 512
#define NN 4096      // 64*64 spatial
#define NRR 1024     // 32*32 spatial (stride-2)
#define NHH 8
#define DKK 64

static __device__ __forceinline__ bf16x8 ld8(const bf16* p) {
    return *reinterpret_cast<const bf16x8*>(p);
}

// ---------------------------------------------------------------------------
// weight convert / permute (fp32 -> bf16)
// ---------------------------------------------------------------------------
__global__ __launch_bounds__(256) void wcvt_kernel(const float* __restrict__ Wq,
                                                   const float* __restrict__ Wp,
                                                   bf16* __restrict__ Wqb,
                                                   bf16* __restrict__ Wpb) {
    int e = blockIdx.x * 256 + threadIdx.x;   // 262144
    Wqb[e] = (bf16)Wq[e];
    Wpb[e] = (bf16)Wp[e];
}

__global__ __launch_bounds__(256) void wperm_kernel(const float* __restrict__ Wk,
                                                    const float* __restrict__ Wv,
                                                    bf16* __restrict__ Wkf,
                                                    bf16* __restrict__ Wvf) {
    int e = blockIdx.x * 256 + threadIdx.x;   // 512*2048
    int o = e >> 11, q = (e >> 9) & 3, ci = e & 511;
    int src = o * 2048 + ci * 4 + q;
    Wkf[e] = (bf16)Wk[src];
    Wvf[e] = (bf16)Wv[src];
}

// ---------------------------------------------------------------------------
// x (b,C,N) fp32 -> xt (b,N,C) bf16; blockIdx.z = batch
// ---------------------------------------------------------------------------
__global__ __launch_bounds__(256) void transpose_kernel(const float* __restrict__ x,
                                                        bf16* __restrict__ xt) {
    __shared__ bf16 tile[64][65];
    int b = blockIdx.z;
    const float* xb = x + (size_t)b * CC * NN;
    bf16* xtb = xt + (size_t)b * NN * CC;
    int n0 = blockIdx.x * 64, c0 = blockIdx.y * 64;
    int tr = threadIdx.x >> 6, tc = threadIdx.x & 63;
#pragma unroll
    for (int i = 0; i < 64; i += 4)
        tile[tc][i + tr] = (bf16)xb[(long)(c0 + i + tr) * NN + n0 + tc];
    __syncthreads();
#pragma unroll
    for (int i = 0; i < 64; i += 4)
        xtb[(long)(n0 + i + tr) * CC + c0 + tc] = tile[i + tr][tc];
}

// ---------------------------------------------------------------------------
// K/V GEMM, im2col fused; blockIdx.z = b*2 + (0=K,1=V)
// ---------------------------------------------------------------------------
__global__ __launch_bounds__(256) void gemm_kv(const bf16* __restrict__ xt,
                                               const bf16* __restrict__ Wkf,
                                               const bf16* __restrict__ Wvf,
                                               bf16* __restrict__ kt,
                                               bf16* __restrict__ vt) {
    const f32x4 fzero = {0.f, 0.f, 0.f, 0.f};
    int z = blockIdx.z;
    int b = z >> 1, kv = z & 1;
    const bf16* xtb = xt + (size_t)b * NN * CC;
    const bf16* Wf = kv ? Wvf : Wkf;
    bf16* Ct = (kv ? vt : kt) + (size_t)b * NRR * CC;
    int w = threadIdx.x >> 6, lane = threadIdx.x & 63;
    int quad = lane >> 4, l15 = lane & 15;
    int m0 = blockIdx.x * 64 + w * 16;
    long n0 = (long)blockIdx.y * 64;
    int m2 = m0 + l15;
    int i2 = m2 >> 5, j2 = m2 & 31;
    const bf16* ap[4];
#pragma unroll
    for (int q = 0; q < 4; ++q) {
        int n = (2 * i2 + (q >> 1)) * 64 + 2 * j2 + (q & 1);
        ap[q] = xtb + (long)n * CC + quad * 8;
    }
    const bf16* Bp = Wf + (n0 + l15) * 2048 + quad * 8;
    f32x4 acc[4];
#pragma unroll
    for (int ct = 0; ct < 4; ++ct) acc[ct] = fzero;
#pragma unroll
    for (int q = 0; q < 4; ++q) {
        const bf16* aq = ap[q];
        const bf16* bq = Bp + q * 512;
#pragma unroll 2
        for (int kk = 0; kk < 512; kk += 32) {
            bf16x8 a = ld8(aq + kk);
#pragma unroll
            for (int ct = 0; ct < 4; ++ct) {
                bf16x8 bv = ld8(bq + kk + ct * 16 * 2048);
                acc[ct] = __builtin_amdgcn_mfma_f32_16x16x32_bf16(a, bv, acc[ct], 0, 0, 0);
            }
        }
    }
#pragma unroll
    for (int ct = 0; ct < 4; ++ct)
#pragma unroll
        for (int r = 0; r < 4; ++r)
            Ct[(long)(m0 + quad * 4 + r) * CC + n0 + ct * 16 + l15] = (bf16)acc[ct][r];
}

// ---------------------------------------------------------------------------
// flash attention with fused Q-GEMM; blockIdx.z = batch
// ---------------------------------------------------------------------------
__global__ __launch_bounds__(256) void attn_kernel(const bf16* __restrict__ xt,
                                                   const bf16* __restrict__ Wqb,
                                                   const bf16* __restrict__ Kt,
                                                   const bf16* __restrict__ Vt,
                                                   const float* __restrict__ bias,
                                                   bf16* __restrict__ Ot) {
    __shared__ __align__(16) bf16 vtile[64 * 64];       // [d][m] xor-swizzled
    __shared__ __align__(16) bf16 ptile[4][16 * 72];    // per-wave Q/P stripe
    const f32x4 fzero = {0.f, 0.f, 0.f, 0.f};
    int b = blockIdx.z, h = blockIdx.y;
    const bf16* xtb = xt + (size_t)b * NN * CC;
    const bf16* Ktb = Kt + (size_t)b * NRR * CC;
    const bf16* Vtb = Vt + (size_t)b * NRR * CC;
    bf16* Otb = Ot + (size_t)b * NN * CC;
    int w = threadIdx.x >> 6, lane = threadIdx.x & 63;
    int quad = lane >> 4, l15 = lane & 15;
    int m0 = blockIdx.x * 64 + w * 16;
    float bh = bias[h];

    // fused Q-GEMM: Q(16x64) = xt(16x512) . Wq_head^T
    f32x4 qacc[4];
#pragma unroll
    for (int ct = 0; ct < 4; ++ct) qacc[ct] = fzero;
    {
        const bf16* axp = xtb + (long)(m0 + l15) * CC + quad * 8;
        const bf16* bwp = Wqb + (long)(h * DKK + l15) * CC + quad * 8;
#pragma unroll 2
        for (int k0 = 0; k0 < 512; k0 += 32) {
            bf16x8 a = ld8(axp + k0);
#pragma unroll
            for (int ct = 0; ct < 4; ++ct) {
                bf16x8 bv = ld8(bwp + k0 + ct * 16 * CC);
                qacc[ct] = __builtin_amdgcn_mfma_f32_16x16x32_bf16(a, bv, qacc[ct], 0, 0, 0);
            }
        }
    }
    // D-layout -> LDS -> A-layout (barrier pins cross-lane RAW)
    bf16* ql = &ptile[w][0];
#pragma unroll
    for (int ct = 0; ct < 4; ++ct)
#pragma unroll
        for (int r = 0; r < 4; ++r)
            ql[(quad * 4 + r) * 72 + ct * 16 + l15] = (bf16)qacc[ct][r];
    __syncthreads();
    bf16x8 aq0 = ld8(ql + l15 * 72 + quad * 8);
    bf16x8 aq1 = ld8(ql + l15 * 72 + 32 + quad * 8);

    f32x4 oacc[4];
    float mrow[4], lrow[4];
#pragma unroll
    for (int r = 0; r < 4; ++r) { mrow[r] = -1e30f; lrow[r] = 0.f; }
#pragma unroll
    for (int ct = 0; ct < 4; ++ct) oacc[ct] = fzero;

    for (int kt = 0; kt < 16; ++kt) {
        __syncthreads();
        // stage V tile transposed + swizzled
#pragma unroll
        for (int it = 0; it < 2; ++it) {
            int idx = threadIdx.x + it * 256;
            int mloc = idx >> 3, d8 = idx & 7;
            bf16x8 v = ld8(Vtb + (long)(kt * 64 + mloc) * CC + h * DKK + d8 * 8);
#pragma unroll
            for (int i = 0; i < 8; ++i) {
                int d = d8 * 8 + i;
                int sw = (((d >> 3) ^ d) & 7) * 8;
                vtile[d * 64 + (mloc ^ sw)] = v[i];
            }
        }
        __syncthreads();

        // S = Q K^T
        f32x4 s[4];
#pragma unroll
        for (int ct = 0; ct < 4; ++ct) s[ct] = fzero;
        const bf16* kp = Ktb + (long)(kt * 64 + l15) * CC + h * DKK + quad * 8;
#pragma unroll
        for (int ct = 0; ct < 4; ++ct) {
            bf16x8 bk0 = ld8(kp + ct * 16 * CC);
            bf16x8 bk1 = ld8(kp + ct * 16 * CC + 32);
            s[ct] = __builtin_amdgcn_mfma_f32_16x16x32_bf16(aq0, bk0, s[ct], 0, 0, 0);
            s[ct] = __builtin_amdgcn_mfma_f32_16x16x32_bf16(aq1, bk1, s[ct], 0, 0, 0);
        }

        // online softmax
        float pv[4][4], tmax[4], rsum[4], alpha[4];
#pragma unroll
        for (int ct = 0; ct < 4; ++ct)
#pragma unroll
            for (int r = 0; r < 4; ++r) pv[ct][r] = s[ct][r] * 0.125f + bh;
#pragma unroll
        for (int r = 0; r < 4; ++r)
            tmax[r] = fmaxf(fmaxf(pv[0][r], pv[1][r]), fmaxf(pv[2][r], pv[3][r]));
#pragma unroll
        for (int off = 1; off < 16; off <<= 1)
#pragma unroll
            for (int r = 0; r < 4; ++r)
                tmax[r] = fmaxf(tmax[r], __shfl_xor(tmax[r], off, 16));
#pragma unroll
        for (int r = 0; r < 4; ++r) {
            float mn = fmaxf(mrow[r], tmax[r]);
            alpha[r] = __expf(mrow[r] - mn);
            mrow[r] = mn;
            rsum[r] = 0.f;
        }
#pragma unroll
        for (int ct = 0; ct < 4; ++ct)
#pragma unroll
            for (int r = 0; r < 4; ++r) {
                pv[ct][r] = __expf(pv[ct][r] - mrow[r]);
                rsum[r] += pv[ct][r];
            }
#pragma unroll
        for (int off = 1; off < 16; off <<= 1)
#pragma unroll
            for (int r = 0; r < 4; ++r)
                rsum[r] += __shfl_xor(rsum[r], off, 16);
#pragma unroll
        for (int r = 0; r < 4; ++r) {
            lrow[r] = lrow[r] * alpha[r] + rsum[r];
#pragma unroll
            for (int ct = 0; ct < 4; ++ct) oacc[ct][r] *= alpha[r];
        }

        // P: D-layout -> LDS -> A-layout
        bf16* pl = &ptile[w][0];
#pragma unroll
        for (int ct = 0; ct < 4; ++ct)
#pragma unroll
            for (int r = 0; r < 4; ++r)
                pl[(quad * 4 + r) * 72 + ct * 16 + l15] = (bf16)pv[ct][r];
        __syncthreads();

        // O += P V
#pragma unroll
        for (int ks = 0; ks < 2; ++ks) {
            bf16x8 ap = ld8(&ptile[w][l15 * 72 + ks * 32 + quad * 8]);
#pragma unroll
            for (int ct = 0; ct < 4; ++ct) {
                int d = ct * 16 + l15;
                int sw = (((d >> 3) ^ d) & 7) * 8;
                bf16x8 bv = ld8(&vtile[d * 64 + ((ks * 32 + quad * 8) ^ sw)]);
                oacc[ct] = __builtin_amdgcn_mfma_f32_16x16x32_bf16(ap, bv, oacc[ct], 0, 0, 0);
            }
        }
    }

    float inv[4];
#pragma unroll
    for (int r = 0; r < 4; ++r) inv[r] = 1.f / lrow[r];
#pragma unroll
    for (int ct = 0; ct < 4; ++ct)
#pragma unroll
        for (int r = 0; r < 4; ++r)
            Otb[(long)(m0 + quad * 4 + r) * CC + h * DKK + ct * 16 + l15] =
                (bf16)(oacc[ct][r] * inv[r]);
}

// ---------------------------------------------------------------------------
// proj: p[b,o,n] = Wproj . ot[b,n,:]^T, fp32 out; blockIdx.z = batch
// ---------------------------------------------------------------------------
__global__ __launch_bounds__(256) void gemm_ntf(const bf16* __restrict__ A,
                                                const bf16* __restrict__ Bt,
                                                float* __restrict__ C) {
    const f32x4 fzero = {0.f, 0.f, 0.f, 0.f};
    int b = blockIdx.z;
    const bf16* Btb = Bt + (size_t)b * NN * CC;
    float* Cb = C + (size_t)b * CC * NN;
    int w = threadIdx.x >> 6, lane = threadIdx.x & 63;
    int quad = lane >> 4, l15 = lane & 15;
    long m0 = (long)blockIdx.x * 64 + w * 16;
    long n0 = (long)blockIdx.y * 64;
    f32x4 acc[4];
#pragma unroll
    for (int ct = 0; ct < 4; ++ct) acc[ct] = fzero;
    const bf16* Ap = A + (m0 + l15) * CC + quad * 8;
    const bf16* Bp = Btb + (n0 + l15) * CC + quad * 8;
#pragma unroll 2
    for (int k0 = 0; k0 < 512; k0 += 32) {
        bf16x8 a = ld8(Ap + k0);
#pragma unroll
        for (int ct = 0; ct < 4; ++ct) {
            bf16x8 bv = ld8(Bp + k0 + (long)ct * 16 * CC);
            acc[ct] = __builtin_amdgcn_mfma_f32_16x16x32_bf16(a, bv, acc[ct], 0, 0, 0);
        }
    }
#pragma unroll
    for (int ct = 0; ct < 4; ++ct)
#pragma unroll
        for (int r = 0; r < 4; ++r)
            Cb[(m0 + quad * 4 + r) * NN + n0 + ct * 16 + l15] = acc[ct][r];
}

// ---------------------------------------------------------------------------
// BN batch stats folded into scale/shift (fp32 p = d_out)
// ---------------------------------------------------------------------------
__global__ __launch_bounds__(256) void bnstats_kernel(const float* __restrict__ p,
                                                      const float* __restrict__ gamma,
                                                      const float* __restrict__ beta,
                                                      float* __restrict__ stats) {
    int c = blockIdx.x, t = threadIdx.x;
    float s = 0.f, ss = 0.f;
    for (int b = 0; b < BB; ++b) {
        const float* base = p + ((long)(b * CC + c)) * NN;
        for (int n = t; n < NN; n += 256) {
            float v = base[n];
            s += v; ss += v * v;
        }
    }
    __shared__ float rs[256], rss[256];
    rs[t] = s; rss[t] = ss;
    __syncthreads();
    for (int st = 128; st > 0; st >>= 1) {
        if (t < st) { rs[t] += rs[t + st]; rss[t] += rss[t + st]; }
        __syncthreads();
    }
    if (t == 0) {
        float mean = rs[0] * (1.f / 16384.f);
        float var = rss[0] * (1.f / 16384.f) - mean * mean;
        float rstd = rsqrtf(var + 1e-5f);
        float sc = gamma[c] * rstd;
        stats[c * 2] = sc;
        stats[c * 2 + 1] = beta[c] - mean * sc;
    }
}

// ---------------------------------------------------------------------------
// y = x + bn(p); LayerNorm over C per pixel; fp32 in-place on d_out
// ---------------------------------------------------------------------------
__global__ __launch_bounds__(256) void final_kernel(const float* __restrict__ x,
                                                    const float* __restrict__ p,
                                                    const float* __restrict__ stats,
                                                    const float* __restrict__ lg,
                                                    const float* __restrict__ lb,
                                                    float* __restrict__ out) {
    int blk = blockIdx.x;
    int b = blk >> 6;
    int pix0 = (blk & 63) * 64;
    int sub = threadIdx.x >> 6, px = threadIdx.x & 63;
    float s = 0.f, ss = 0.f;
    for (int i = 0; i < 128; ++i) {
        int c = i * 4 + sub;
        long idx = ((long)(b * CC + c)) * NN + pix0 + px;
        float y = x[idx] + p[idx] * stats[c * 2] + stats[c * 2 + 1];
        s += y; ss += y * y;
    }
    __shared__ float rs[4][64], rss[4][64];
    rs[sub][px] = s; rss[sub][px] = ss;
    __syncthreads();
    float sum = rs[0][px] + rs[1][px] + rs[2][px] + rs[3][px];
    float sq  = rss[0][px] + rss[1][px] + rss[2][px] + rss[3][px];
    float mu = sum * (1.f / 512.f);
    float var = sq * (1.f / 512.f) - mu * mu;
    float rstd = rsqrtf(var + 1e-5f);
    for (int i = 0; i < 128; ++i) {
        int c = i * 4 + sub;
        long idx = ((long)(b * CC + c)) * NN + pix0 + px;
        float y = x[idx] + p[idx] * stats[c * 2] + stats[c * 2 + 1];
        out[idx] = (y - mu) * rstd * lg[c] + lb[c];
    }
}

// ---------------------------------------------------------------------------
extern "C" void kernel_launch(void* const* d_in, const int* in_sizes, int n_in,
                              void* d_out, int out_size, void* d_ws, size_t ws_size,
                              hipStream_t stream) {
    (void)in_sizes; (void)n_in; (void)out_size;
    const float* x     = (const float*)d_in[0];
    const float* Wq    = (const float*)d_in[1];
    const float* Wk    = (const float*)d_in[2];
    const float* Wv    = (const float*)d_in[3];
    const float* bias  = (const float*)d_in[4];
    const float* Wproj = (const float*)d_in[5];
    const float* bng   = (const float*)d_in[6];
    const float* bnb   = (const float*)d_in[7];
    const float* lng   = (const float*)d_in[8];
    const float* lnb   = (const float*)d_in[9];
    float* out = (float*)d_out;   // fp32 output (verified R9)

    char* ws = (char*)d_ws;
    size_t off = 0;
    auto alloc = [&](size_t bytes) {
        char* pp = ws + off;
        off += (bytes + 255) & ~(size_t)255;
        return pp;
    };
    bf16* Wqb = (bf16*)alloc((size_t)CC * CC * 2);          // 0.52 MB
    bf16* Wpb = (bf16*)alloc((size_t)CC * CC * 2);          // 0.52 MB
    float* stats = (float*)alloc(512 * 2 * sizeof(float));

    // Layout A (fully batched) needs ~47 MB; layout B (per-batch) ~11.6 MB.
    size_t needA = off + ((size_t)CC * 2048 * 2 * 2)        // Wkf+Wvf 4.2 MB
                 + ((size_t)BB * NN * CC * 2)               // xt_all 16.8
                 + ((size_t)BB * NRR * CC * 2 * 2)          // kt+vt   8.4
                 + ((size_t)BB * NN * CC * 2) + 4096;       // ot_all 16.8

    if (ws_size >= needA) {
        // ---- layout A: one launch per stage, full batch in grid.z ----
        bf16* Wkf = (bf16*)alloc((size_t)CC * 2048 * 2);
        bf16* Wvf = (bf16*)alloc((size_t)CC * 2048 * 2);
        bf16* xt  = (bf16*)alloc((size_t)BB * NN * CC * 2);
        bf16* kt  = (bf16*)alloc((size_t)BB * NRR * CC * 2);
        bf16* vt  = (bf16*)alloc((size_t)BB * NRR * CC * 2);
        bf16* ot  = (bf16*)alloc((size_t)BB * NN * CC * 2);

        wcvt_kernel<<<1024, 256, 0, stream>>>(Wq, Wproj, Wqb, Wpb);
        wperm_kernel<<<4096, 256, 0, stream>>>(Wk, Wv, Wkf, Wvf);
        transpose_kernel<<<dim3(64, 8, BB), 256, 0, stream>>>(x, xt);
        gemm_kv<<<dim3(16, 8, BB * 2), 256, 0, stream>>>(xt, Wkf, Wvf, kt, vt);
        attn_kernel<<<dim3(64, NHH, BB), 256, 0, stream>>>(xt, Wqb, kt, vt, bias, ot);
        gemm_ntf<<<dim3(8, 64, BB), 256, 0, stream>>>(Wpb, ot, out);
    } else {
        // ---- layout B: per-batch loop, Wkf/Wvf overlay out slice 3 ----
        bf16* Wkf = (bf16*)(out + (size_t)3 * CC * NN);
        bf16* Wvf = Wkf + (size_t)CC * 2048;
        bf16* xt = (bf16*)alloc((size_t)NN * CC * 2);
        bf16* kt = (bf16*)alloc((size_t)NRR * CC * 2);
        bf16* vt = (bf16*)alloc((size_t)NRR * CC * 2);
        bf16* ot = (bf16*)alloc((size_t)NN * CC * 2);

        wcvt_kernel<<<1024, 256, 0, stream>>>(Wq, Wproj, Wqb, Wpb);
        wperm_kernel<<<4096, 256, 0, stream>>>(Wk, Wv, Wkf, Wvf);
        for (int b = 0; b < BB; ++b) {
            const float* xb = x + (size_t)b * CC * NN;
            float* pb = out + (size_t)b * CC * NN;
            transpose_kernel<<<dim3(64, 8, 1), 256, 0, stream>>>(xb, xt);
            gemm_kv<<<dim3(16, 8, 2), 256, 0, stream>>>(xt, Wkf, Wvf, kt, vt);
            attn_kernel<<<dim3(64, NHH, 1), 256, 0, stream>>>(xt, Wqb, kt, vt, bias, ot);
            gemm_ntf<<<dim3(8, 64, 1), 256, 0, stream>>>(Wpb, ot, pb);
        }
    }

    bnstats_kernel<<<512, 256, 0, stream>>>(out, bng, bnb, stats);
    final_kernel<<<256, 256, 0, stream>>>(x, out, stats, lng, lnb, out);
}